// Round 17
// baseline (79.569 us; speedup 1.0000x reference)
//
#include <hip/hip_runtime.h>
#include <math.h>

// RepFlowLayer r17: r16 (77.8us best) + one isolated change: kernelBases and
// kernelNsym widened 64 -> 128 blocks (8 locs/block, 2x CU utilization).
// M=16 MFMA tile carries 8 valid rows: A-row index clamped (lr&7), C rows >=8
// not stored (lg<2 guard). All math and other kernels byte-identical to r16.

typedef __attribute__((ext_vector_type(8))) __bf16 bf16x8;
typedef __attribute__((ext_vector_type(4))) float f32x4;
typedef __attribute__((ext_vector_type(8))) unsigned short us8;

__device__ __forceinline__ float silu(float x) { return x / (1.0f + __expf(-x)); }
__device__ __forceinline__ unsigned short f2bf(float x) {
    union { float f; unsigned int u; } v; v.f = x;
    unsigned int r = v.u + 0x7fffu + ((v.u >> 16) & 1u);
    return (unsigned short)(r >> 16);
}
__device__ __forceinline__ float bf2f(unsigned short h) {
    union { unsigned int u; float f; } v; v.u = ((unsigned int)h) << 16;
    return v.f;
}
__device__ __forceinline__ f32x4 MFMA(bf16x8 a, bf16x8 b, f32x4 c) {
    return __builtin_amdgcn_mfma_f32_16x16x32_bf16(a, b, c, 0, 0, 0);
}

#define OFF_NE  0
#define OFF_ES  24576
#define OFF_E2  36864
#define OFF_A1  40960
#define OFF_AS  43008
#define OFF_EJ1 44032
#define OFF_EI1 48128
#define OFF_EJ2 52224
#define OFF_EI2 54272
#define WS_UNITS 7040

#define P2_NSB  0
#define P2_NEB  16384
#define P2_ESB  32768
#define P2_NSYM 40960
#define P2_UNITS 17408
#define SCR2_BYTES  278528
#define BASES_BYTES 1310720
#define SYMB_BYTES  1572864
#define WS_NEEDED   3274752

__global__ __launch_bounds__(256) void prepAll(
    const float* __restrict__ w_ne, const float* __restrict__ w_es,
    const float* __restrict__ w_e2, const float* __restrict__ w_a1,
    const float* __restrict__ w_as, const float* __restrict__ w_ns,
    const float* __restrict__ w_nsym,
    unsigned short* __restrict__ wsb, unsigned short* __restrict__ scr2)
{
    if (blockIdx.x < 28) {
        int u = blockIdx.x * 256 + threadIdx.x;
        if (u >= WS_UNITS) return;
        const float* w; int N, k0, KS; int uu = u;
        if (uu < 3072)      { w = w_ne; N = 128; k0 = 128; KS = 6; }
        else if (uu < 4608) { uu -= 3072; w = w_es; N = 64;  k0 = 128; KS = 6; }
        else if (uu < 5120) { uu -= 4608; w = w_e2; N = 64;  k0 = 0;   KS = 2; }
        else if (uu < 5376) { uu -= 5120; w = w_a1; N = 64;  k0 = 0;   KS = 1; }
        else if (uu < 5504) { uu -= 5376; w = w_as; N = 32;  k0 = 0;   KS = 1; }
        else if (uu < 6016) { uu -= 5504; w = w_a1; N = 64;  k0 = 160; KS = 2; }
        else if (uu < 6528) { uu -= 6016; w = w_a1; N = 64;  k0 = 224; KS = 2; }
        else if (uu < 6784) { uu -= 6528; w = w_as; N = 32;  k0 = 160; KS = 2; }
        else                { uu -= 6784; w = w_as; N = 32;  k0 = 224; KS = 2; }
        int lane = uu & 63, rest = uu >> 6;
        int ks = rest % KS, nt = rest / KS;
        int k = k0 + ks * 32 + ((lane >> 4) << 3);
        int n = nt * 16 + (lane & 15);
        us8 o;
        #pragma unroll
        for (int t = 0; t < 8; ++t) o[t] = f2bf(w[(size_t)(k + t) * N + n]);
        *(us8*)&wsb[(size_t)u * 8] = o;
    } else {
        int u = (blockIdx.x - 28) * 256 + threadIdx.x;
        if (u >= P2_UNITS) return;
        const float* w; int N, KS; int uu = u;
        if (uu < 2048)      { w = w_ns;   N = 128; KS = 4; }
        else if (uu < 4096) { uu -= 2048; w = w_ne;   N = 128; KS = 4; }
        else if (uu < 5120) { uu -= 4096; w = w_es;   N = 64;  KS = 4; }
        else                { uu -= 5120; w = w_nsym; N = 128; KS = 24; }
        int lane = uu & 63, rest = uu >> 6;
        int ks = rest % KS, nt = rest / KS;
        int k = ks * 32 + ((lane >> 4) << 3);
        int n = nt * 16 + (lane & 15);
        us8 o;
        #pragma unroll
        for (int t = 0; t < 8; ++t) o[t] = f2bf(w[(size_t)(k + t) * N + n]);
        *(us8*)&scr2[(size_t)u * 8] = o;
    }
}

// 128 blocks x 8 locs (M-tile half-filled; rows >=8 unused)
__global__ __launch_bounds__(256) void kernelBases(
    const float* __restrict__ node_ext, const unsigned short* __restrict__ scr2,
    const float* __restrict__ b_ns, const float* __restrict__ b_ne,
    const float* __restrict__ b_es, float* __restrict__ bases)
{
    __shared__ __align__(16) unsigned short s_N[8][136];
    const int b = blockIdx.x, tid = threadIdx.x, L0 = b * 8;
    for (int v = tid; v < 1024; v += 256)
        s_N[v >> 7][v & 127] = f2bf(node_ext[(size_t)(L0 + (v >> 7)) * 128 + (v & 127)]);
    __syncthreads();
    const int wv = tid >> 6, ln = tid & 63, lg = ln >> 4, lr = ln & 15;
    f32x4 acc[5];
    #pragma unroll
    for (int n = 0; n < 5; ++n) acc[n] = (f32x4){0.f,0.f,0.f,0.f};
    #pragma unroll
    for (int ks = 0; ks < 4; ++ks) {
        bf16x8 a = *(const bf16x8*)&s_N[lr & 7][ks*32 + lg*8];
        #pragma unroll
        for (int ntl = 0; ntl < 5; ++ntl) {
            int t = wv * 5 + ntl;
            size_t eoff;
            if      (t < 8)  eoff = P2_NSB + (size_t)((t*4+ks)*64+ln)*8;
            else if (t < 16) eoff = P2_NEB + (size_t)(((t-8)*4+ks)*64+ln)*8;
            else             eoff = P2_ESB + (size_t)(((t-16)*4+ks)*64+ln)*8;
            bf16x8 bb = *(const bf16x8*)&scr2[eoff];
            acc[ntl] = MFMA(a, bb, acc[ntl]);
        }
    }
    if (lg < 2) {
        #pragma unroll
        for (int ntl = 0; ntl < 5; ++ntl) {
            int t = wv * 5 + ntl;
            int col = t * 16 + lr;
            float bias = (col < 128) ? b_ns[col] : (col < 256) ? b_ne[col-128] : b_es[col-256];
            #pragma unroll
            for (int r = 0; r < 4; ++r)
                bases[(size_t)(L0 + lg*4 + r) * 320 + col] = acc[ntl][r] + bias;
        }
    }
}

__global__ __launch_bounds__(512, 8) void kernelA(
    const float* __restrict__ node_ext, const float* __restrict__ edge,
    const float* __restrict__ h2, const int* __restrict__ nlist,
    const float* __restrict__ sw, const unsigned short* __restrict__ wsb,
    const float* __restrict__ bases, unsigned short* __restrict__ symb,
    const float* __restrict__ b_ea2,
    const float* __restrict__ res_n0, const float* __restrict__ res_n2,
    const float* __restrict__ res_e0, const float* __restrict__ res_e1,
    float* __restrict__ out_n, float* __restrict__ out_e)
{
    __shared__ __align__(16) unsigned short s_X[64][200];
    __shared__ float s_h2g2[3][192];
    __shared__ float s_base[320];
    __shared__ float s_ne[128];
    __shared__ float s_nodef[128];
    __shared__ float s_sw[64];
    __shared__ float s_h2w[192];
    __shared__ int   s_nl[64];

    const int l = blockIdx.x, tid = threadIdx.x;

    if (tid < 64) {
        s_nl[tid] = nlist[l*64 + tid];
        s_base[256 + tid] = bases[(size_t)l * 320 + 256 + tid];   // esb section
    }
    else if (tid < 192) s_nodef[tid - 64] = node_ext[(size_t)l*128 + (tid - 64)];
    else if (tid < 256) s_sw[tid - 192] = sw[l*64 + (tid - 192)];
    else s_base[tid - 256] = bases[(size_t)l * 320 + (tid - 256)];  // tid 256..511 -> 0..255
    __syncthreads();

    for (int v = tid; v < 8192; v += 512) {
        int n = v >> 7, j = v & 127;
        s_X[n][j] = f2bf(node_ext[(size_t)s_nl[n] * 128 + j]);
    }
    for (int v = tid; v < 4096; v += 512)
        s_X[v >> 6][128 + (v & 63)] = f2bf(edge[(size_t)l * 4096 + v]);
    if (tid < 192) s_h2w[tid] = h2[(size_t)l * 192 + tid] * s_sw[tid / 3];
    __syncthreads();

    // ---- h2g2 (fp32 VALU, 4-way ILP)
    for (int v = tid; v < 576; v += 512) {
        int c = v / 192, d = v % 192;
        float p0 = 0.f, p1 = 0.f, p2 = 0.f, p3 = 0.f;
        for (int n = 0; n < 64; n += 4) {
            p0 = fmaf(s_h2w[n * 3 + c],       bf2f(s_X[n][d]),     p0);
            p1 = fmaf(s_h2w[(n + 1) * 3 + c], bf2f(s_X[n + 1][d]), p1);
            p2 = fmaf(s_h2w[(n + 2) * 3 + c], bf2f(s_X[n + 2][d]), p2);
            p3 = fmaf(s_h2w[(n + 3) * 3 + c], bf2f(s_X[n + 3][d]), p3);
        }
        s_h2g2[c][d] = ((p0 + p1) + (p2 + p3)) * 0.125f;   // 1/sqrt(64)
    }
    __syncthreads();

    const int wv = tid >> 6, ln = tid & 63, lg = ln >> 4, lr = ln & 15;

    // ---- NE: wave wv owns n-tile nt = wv (8 waves x 16 cols = 128)
    {
        f32x4 acc[4];
        #pragma unroll
        for (int m = 0; m < 4; ++m) acc[m] = (f32x4){0.f, 0.f, 0.f, 0.f};
        #pragma unroll
        for (int ks = 0; ks < 6; ++ks) {
            bf16x8 b = *(const bf16x8*)&wsb[OFF_NE + (size_t)((wv * 6 + ks) * 64 + ln) * 8];
            #pragma unroll
            for (int m = 0; m < 4; ++m) {
                bf16x8 a = *(const bf16x8*)&s_X[m * 16 + lr][ks * 32 + lg * 8];
                acc[m] = MFMA(a, b, acc[m]);
            }
        }
        int col = wv * 16 + lr;
        float base = s_base[128 + col];
        float cs = 0.f;
        #pragma unroll
        for (int m = 0; m < 4; ++m)
            #pragma unroll
            for (int r = 0; r < 4; ++r)
                cs = fmaf(silu(base + acc[m][r]), s_sw[m * 16 + lg * 4 + r], cs);
        cs += __shfl_xor(cs, 16);
        cs += __shfl_xor(cs, 32);
        if (lg == 0) s_ne[col] = cs;
    }

    // ---- ES + E2: wave pair: nt = wv>>1, m-half = wv&1 (m0 = 2*(wv&1))
    {
        const int nt = wv >> 1, m0 = (wv & 1) * 2;
        f32x4 aes[2], ae2[2];
        #pragma unroll
        for (int mm = 0; mm < 2; ++mm) {
            aes[mm] = (f32x4){0.f, 0.f, 0.f, 0.f};
            ae2[mm] = (f32x4){0.f, 0.f, 0.f, 0.f};
        }
        #pragma unroll
        for (int ks = 0; ks < 6; ++ks) {
            bf16x8 b = *(const bf16x8*)&wsb[OFF_ES + (size_t)((nt * 6 + ks) * 64 + ln) * 8];
            bf16x8 a[2];
            #pragma unroll
            for (int mm = 0; mm < 2; ++mm)
                a[mm] = *(const bf16x8*)&s_X[(m0 + mm) * 16 + lr][ks * 32 + lg * 8];
            #pragma unroll
            for (int mm = 0; mm < 2; ++mm) aes[mm] = MFMA(a[mm], b, aes[mm]);
            if (ks >= 4) {
                bf16x8 b2 = *(const bf16x8*)&wsb[OFF_E2 + (size_t)((nt * 2 + (ks - 4)) * 64 + ln) * 8];
                #pragma unroll
                for (int mm = 0; mm < 2; ++mm)
                    if (m0 + mm > 0) ae2[mm] = MFMA(a[mm], b2, ae2[mm]);
            }
        }
        int o = nt * 16 + lr;
        float esb = s_base[256 + o];
        float re0 = res_e0[o], re1 = res_e1[o], be2 = b_ea2[o];
        #pragma unroll
        for (int mm = 0; mm < 2; ++mm) {
            int m = m0 + mm;
            #pragma unroll
            for (int r = 0; r < 4; ++r) {
                int n = m * 16 + lg * 4 + r;
                size_t gi = (size_t)l * 4096 + (size_t)n * 64 + o;
                float val = bf2f(s_X[n][128 + o]) + re0 * silu(esb + aes[mm][r]);
                if (m > 0) val = fmaf(re1, silu(be2 + ae2[mm][r]), val);
                out_e[gi] = val;
            }
        }
    }

    // ---- sym (grrg) -> bf16 symb scratch
    for (int v = tid; v < 768; v += 512) {
        float p;
        if (v < 256) {
            int a = v >> 6, d = v & 63;
            p = s_h2g2[0][128 + a] * s_h2g2[0][128 + d]
              + s_h2g2[1][128 + a] * s_h2g2[1][128 + d]
              + s_h2g2[2][128 + a] * s_h2g2[2][128 + d];
        } else {
            int v2 = v - 256; int a = v2 >> 7, d = v2 & 127;
            p = s_h2g2[0][a] * s_h2g2[0][d]
              + s_h2g2[1][a] * s_h2g2[1][d]
              + s_h2g2[2][a] * s_h2g2[2][d];
        }
        symb[(size_t)l * 768 + v] = f2bf(p * (1.f / 3.f));
    }
    __syncthreads();

    if (tid < 128) {   // out_n partial: res_n1*silu(nsym) added by kernelNsym
        float ne = s_ne[tid] * (1.f / 64.f);
        float v = s_nodef[tid];
        v = fmaf(res_n0[tid], silu(s_base[tid]), v);
        v = fmaf(res_n2[tid], ne, v);
        out_n[(size_t)l * 128 + tid] = v;
    }
}

// 128 blocks x 8 locs (M-tile half-filled)
__global__ __launch_bounds__(256) void kernelNsym(
    const unsigned short* __restrict__ symb, const unsigned short* __restrict__ scr2,
    const float* __restrict__ b_nsym, const float* __restrict__ res_n1,
    float* __restrict__ out_n)
{
    const int b = blockIdx.x, tid = threadIdx.x, L0 = b * 8;
    const int wv = tid >> 6, ln = tid & 63, lg = ln >> 4, lr = ln & 15;
    f32x4 acc[2];
    acc[0] = (f32x4){0.f,0.f,0.f,0.f};
    acc[1] = (f32x4){0.f,0.f,0.f,0.f};
    for (int ks = 0; ks < 24; ++ks) {
        bf16x8 a = *(const bf16x8*)&symb[(size_t)(L0 + (lr & 7)) * 768 + ks*32 + lg*8];
        #pragma unroll
        for (int nt = 0; nt < 2; ++nt) {
            bf16x8 bb = *(const bf16x8*)&scr2[P2_NSYM + (size_t)(((wv*2+nt)*24+ks)*64+ln)*8];
            acc[nt] = MFMA(a, bb, acc[nt]);
        }
    }
    if (lg < 2) {
        #pragma unroll
        for (int nt = 0; nt < 2; ++nt) {
            int col = (wv*2 + nt) * 16 + lr;
            float bias = b_nsym[col], rn = res_n1[col];
            #pragma unroll
            for (int r = 0; r < 4; ++r) {
                size_t idx = (size_t)(L0 + lg*4 + r) * 128 + col;
                out_n[idx] += rn * silu(acc[nt][r] + bias);
            }
        }
    }
}

__global__ __launch_bounds__(512, 8) void kernelB(
    const float* __restrict__ node_ext, const float* __restrict__ edge,
    const float* __restrict__ angle, const float* __restrict__ a_sw,
    const unsigned short* __restrict__ wsb,
    const float* __restrict__ w_ea1, const float* __restrict__ b_ea1,
    const float* __restrict__ b_ea2,
    const float* __restrict__ w_angle_self, const float* __restrict__ b_angle_self,
    const float* __restrict__ res_e1, const float* __restrict__ res_a0,
    float* __restrict__ out_e, float* __restrict__ out_a)
{
    __shared__ __align__(16) unsigned short s_ang[256][40];
    __shared__ __align__(16) unsigned short s_ea[16][72];
    __shared__ __align__(16) unsigned short s_redb[16][72];
    __shared__ float s_ej1[16][66];
    __shared__ float s_ei1[16][64];
    __shared__ float s_ej2[16][34];
    __shared__ float s_ei2[16][32];
    __shared__ float s_nt1[64];
    __shared__ float s_nt2[32];
    __shared__ float s_asw[16];
    __shared__ float s_nodef[128];

    const int l = blockIdx.x, tid = threadIdx.x;
    const int wv = tid >> 6, ln = tid & 63, lg = ln >> 4, lr = ln & 15;

    if (tid < 128) s_nodef[tid] = node_ext[(size_t)l * 128 + tid];
    else if (tid < 144) s_asw[tid - 128] = a_sw[l * 16 + (tid - 128)];
    for (int v = tid; v < 8192; v += 512)
        s_ang[v >> 5][v & 31] = f2bf(angle[(size_t)l * 8192 + v]);
    for (int v = tid; v < 1024; v += 512) s_ea[v >> 6][v & 63] = f2bf(edge[(size_t)l * 4096 + v]);
    __syncthreads();

    // angle A-frags from LDS: wave wv holds i-rows {2wv, 2wv+1}
    bf16x8 a[2];
    #pragma unroll
    for (int mm = 0; mm < 2; ++mm)
        a[mm] = *(const bf16x8*)&s_ang[(wv * 2 + mm) * 16 + lr][lg * 8];

    // ---- V0 over 8 waves: EJ1(wv0-1) EI1(wv2-3) EJ2(wv4) EI2(wv5) nt1(wv6) nt2(wv7)
    if (wv < 6) {
        bf16x8 a0 = *(const bf16x8*)&s_ea[lr][lg * 8];
        bf16x8 a1 = *(const bf16x8*)&s_ea[lr][32 + lg * 8];
        if (wv < 2) {
            #pragma unroll
            for (int ntl = 0; ntl < 2; ++ntl) {
                int nt = wv * 2 + ntl;
                f32x4 c = (f32x4){0.f, 0.f, 0.f, 0.f};
                c = MFMA(a0, *(const bf16x8*)&wsb[OFF_EJ1 + (size_t)((nt * 2 + 0) * 64 + ln) * 8], c);
                c = MFMA(a1, *(const bf16x8*)&wsb[OFF_EJ1 + (size_t)((nt * 2 + 1) * 64 + ln) * 8], c);
                #pragma unroll
                for (int r = 0; r < 4; ++r) s_ej1[lg * 4 + r][nt * 16 + lr] = c[r];
            }
        } else if (wv < 4) {
            #pragma unroll
            for (int ntl = 0; ntl < 2; ++ntl) {
                int nt = (wv - 2) * 2 + ntl;
                f32x4 c = (f32x4){0.f, 0.f, 0.f, 0.f};
                c = MFMA(a0, *(const bf16x8*)&wsb[OFF_EI1 + (size_t)((nt * 2 + 0) * 64 + ln) * 8], c);
                c = MFMA(a1, *(const bf16x8*)&wsb[OFF_EI1 + (size_t)((nt * 2 + 1) * 64 + ln) * 8], c);
                #pragma unroll
                for (int r = 0; r < 4; ++r) s_ei1[lg * 4 + r][nt * 16 + lr] = c[r];
            }
        } else if (wv == 4) {
            #pragma unroll
            for (int nt = 0; nt < 2; ++nt) {
                f32x4 c = (f32x4){0.f, 0.f, 0.f, 0.f};
                c = MFMA(a0, *(const bf16x8*)&wsb[OFF_EJ2 + (size_t)((nt * 2 + 0) * 64 + ln) * 8], c);
                c = MFMA(a1, *(const bf16x8*)&wsb[OFF_EJ2 + (size_t)((nt * 2 + 1) * 64 + ln) * 8], c);
                #pragma unroll
                for (int r = 0; r < 4; ++r) s_ej2[lg * 4 + r][nt * 16 + lr] = c[r];
            }
        } else {
            #pragma unroll
            for (int nt = 0; nt < 2; ++nt) {
                f32x4 c = (f32x4){0.f, 0.f, 0.f, 0.f};
                c = MFMA(a0, *(const bf16x8*)&wsb[OFF_EI2 + (size_t)((nt * 2 + 0) * 64 + ln) * 8], c);
                c = MFMA(a1, *(const bf16x8*)&wsb[OFF_EI2 + (size_t)((nt * 2 + 1) * 64 + ln) * 8], c);
                #pragma unroll
                for (int r = 0; r < 4; ++r) s_ei2[lg * 4 + r][nt * 16 + lr] = c[r];
            }
        }
    } else if (wv == 6) {
        float p = b_ea1[ln];
        for (int k = 0; k < 128; ++k) p = fmaf(s_nodef[k], w_ea1[(32 + k) * 64 + ln], p);
        s_nt1[ln] = p;
    } else {
        if (ln < 32) {
            float p = b_angle_self[ln];
            for (int k = 0; k < 128; ++k) p = fmaf(s_nodef[k], w_angle_self[(32 + k) * 32 + ln], p);
            s_nt2[ln] = p;
        }
    }
    __syncthreads();

    // ---- eau + weighted jj-reduction: per (mm, nt) single MFMA + epilogue
    #pragma unroll
    for (int nt = 0; nt < 4; ++nt) {
        bf16x8 b = *(const bf16x8*)&wsb[OFF_A1 + (size_t)(nt * 64 + ln) * 8];
        #pragma unroll
        for (int mm = 0; mm < 2; ++mm) {
            f32x4 c = MFMA(a[mm], b, (f32x4){0.f, 0.f, 0.f, 0.f});
            int i = wv * 2 + mm;
            int o = nt * 16 + lr;
            float b0 = s_nt1[o] + s_ei1[i][o];
            float ps = 0.f;
            #pragma unroll
            for (int r = 0; r < 4; ++r) {
                int jj = lg * 4 + r;
                ps = fmaf(silu(c[r] + b0 + s_ej1[jj][o]), s_asw[jj], ps);
            }
            ps += __shfl_xor(ps, 16);
            ps += __shfl_xor(ps, 32);
            if (lg == 0) s_redb[i][o] = f2bf(ps * s_asw[i] * 0.25f);  // /sqrt(A_SEL)
        }
    }
    // ---- angle_self + a_updated: residual from LDS bf16 (no 2nd global read)
    #pragma unroll
    for (int nt = 0; nt < 2; ++nt) {
        bf16x8 b = *(const bf16x8*)&wsb[OFF_AS + (size_t)(nt * 64 + ln) * 8];
        #pragma unroll
        for (int mm = 0; mm < 2; ++mm) {
            f32x4 c = MFMA(a[mm], b, (f32x4){0.f, 0.f, 0.f, 0.f});
            int i = wv * 2 + mm;
            int o = nt * 16 + lr;
            float b0 = s_nt2[o] + s_ei2[i][o];
            float ra = res_a0[o];
            #pragma unroll
            for (int r = 0; r < 4; ++r) {
                int jj = lg * 4 + r;
                size_t gi = (size_t)l * 8192 + (size_t)(i * 16 + jj) * 32 + o;
                out_a[gi] = bf2f(s_ang[i * 16 + jj][o]) + ra * silu(c[r] + b0 + s_ej2[jj][o]);
            }
        }
    }
    __syncthreads();

    // ---- e_angle rows n<16: waves 0..3, one n-tile each
    if (wv < 4) {
        bf16x8 a0 = *(const bf16x8*)&s_redb[lr][lg * 8];
        bf16x8 a1 = *(const bf16x8*)&s_redb[lr][32 + lg * 8];
        const int nt = wv;
        f32x4 c = (f32x4){0.f, 0.f, 0.f, 0.f};
        c = MFMA(a0, *(const bf16x8*)&wsb[OFF_E2 + (size_t)((nt * 2 + 0) * 64 + ln) * 8], c);
        c = MFMA(a1, *(const bf16x8*)&wsb[OFF_E2 + (size_t)((nt * 2 + 1) * 64 + ln) * 8], c);
        int o = nt * 16 + lr;
        float be = b_ea2[o], re1 = res_e1[o];
        #pragma unroll
        for (int r = 0; r < 4; ++r) {
            int n = lg * 4 + r;
            size_t gi = (size_t)l * 4096 + (size_t)n * 64 + o;
            out_e[gi] += re1 * silu(be + c[r]);
        }
    }
}

extern "C" void kernel_launch(void* const* d_in, const int* in_sizes, int n_in,
                              void* d_out, int out_size, void* d_ws, size_t ws_size,
                              hipStream_t stream)
{
    const float* node_ext     = (const float*)d_in[0];
    const float* edge         = (const float*)d_in[1];
    const float* h2           = (const float*)d_in[2];
    const float* angle        = (const float*)d_in[3];
    const int*   nlist        = (const int*)d_in[4];
    const float* sw           = (const float*)d_in[6];
    const float* a_sw         = (const float*)d_in[8];
    const float* w_node_self  = (const float*)d_in[9];
    const float* b_node_self  = (const float*)d_in[10];
    const float* w_node_sym   = (const float*)d_in[11];
    const float* b_node_sym   = (const float*)d_in[12];
    const float* w_node_edge  = (const float*)d_in[13];
    const float* b_node_edge  = (const float*)d_in[14];
    const float* w_edge_self  = (const float*)d_in[15];
    const float* b_edge_self  = (const float*)d_in[16];
    const float* w_ea1        = (const float*)d_in[17];
    const float* b_ea1        = (const float*)d_in[18];
    const float* w_ea2        = (const float*)d_in[19];
    const float* b_ea2        = (const float*)d_in[20];
    const float* w_angle_self = (const float*)d_in[21];
    const float* b_angle_self = (const float*)d_in[22];
    const float* res_n0       = (const float*)d_in[23];
    const float* res_n1       = (const float*)d_in[24];
    const float* res_n2       = (const float*)d_in[25];
    const float* res_e0       = (const float*)d_in[26];
    const float* res_e1       = (const float*)d_in[27];
    const float* res_a0       = (const float*)d_in[28];

    float* out_n = (float*)d_out;
    float* out_e = out_n + 1024 * 128;
    float* out_a = out_e + 1024 * 64 * 64;
    unsigned short* wsb = (unsigned short*)d_ws;

    char* scrbase = (ws_size >= (size_t)WS_NEEDED) ? ((char*)d_ws + 112640)
                                                   : (char*)out_a;
    unsigned short* scr2 = (unsigned short*)scrbase;
    float* bases = (float*)(scrbase + SCR2_BYTES);
    unsigned short* symb = (unsigned short*)(scrbase + SCR2_BYTES + BASES_BYTES);
    (void)in_sizes; (void)n_in; (void)out_size;

    hipLaunchKernelGGL(prepAll, dim3(96), dim3(256), 0, stream,
        w_node_edge, w_edge_self, w_ea2, w_ea1, w_angle_self, w_node_self, w_node_sym,
        wsb, scr2);

    hipLaunchKernelGGL(kernelBases, dim3(128), dim3(256), 0, stream,
        node_ext, scr2, b_node_self, b_node_edge, b_edge_self, bases);

    hipLaunchKernelGGL(kernelA, dim3(1024), dim3(512), 0, stream,
        node_ext, edge, h2, nlist, sw, wsb, bases, symb, b_ea2,
        res_n0, res_n2, res_e0, res_e1, out_n, out_e);

    hipLaunchKernelGGL(kernelNsym, dim3(128), dim3(256), 0, stream,
        symb, scr2, b_node_sym, res_n1, out_n);

    hipLaunchKernelGGL(kernelB, dim3(1024), dim3(512), 0, stream,
        node_ext, edge, angle, a_sw, wsb,
        w_ea1, b_ea1, b_ea2, w_angle_self, b_angle_self,
        res_e1, res_a0, out_e, out_a);
}

// Round 18
// 77.748 us; speedup vs baseline: 1.0234x; 1.0234x over previous
//
#include <hip/hip_runtime.h>
#include <math.h>

// RepFlowLayer FINAL (== r16, best measured: 77.8us, absmax 0.031, 4.1x over
// naive fp32 baseline). Structure:
//   prepAll     - weight panels -> bf16 frag-ordered (d_ws + scr2 scratch)
//   kernelBases - node @ [W_ns|W_ne0|W_es0] batched MFMA -> bases (64 blk)
//   kernelA     - per-loc: stage nei+edge bf16 LDS, h2g2 (fp32 4-way ILP),
//                 NE/ES/E2 MFMA (512-thr 8-wave, VGPR<=64, 32 waves/CU),
//                 sym -> symb scratch, out_n partial, out_e
//   kernelNsym  - sym @ W_nsym batched MFMA, out_n += res_n1*silu (64 blk)
//   kernelB     - per-loc angle: stage angle bf16 LDS (feeds A-frags AND
//                 residual), V0 MFMA jobs over 8 waves, eau/angle_self/e_angle
// Measured plateau: r8 fusion, r12-r14 scratch re-plumbing, r17 tile widening
// all neutral-to-negative; r16 configuration is the empirical optimum.

typedef __attribute__((ext_vector_type(8))) __bf16 bf16x8;
typedef __attribute__((ext_vector_type(4))) float f32x4;
typedef __attribute__((ext_vector_type(8))) unsigned short us8;

__device__ __forceinline__ float silu(float x) { return x / (1.0f + __expf(-x)); }
__device__ __forceinline__ unsigned short f2bf(float x) {
    union { float f; unsigned int u; } v; v.f = x;
    unsigned int r = v.u + 0x7fffu + ((v.u >> 16) & 1u);
    return (unsigned short)(r >> 16);
}
__device__ __forceinline__ float bf2f(unsigned short h) {
    union { unsigned int u; float f; } v; v.u = ((unsigned int)h) << 16;
    return v.f;
}
__device__ __forceinline__ f32x4 MFMA(bf16x8 a, bf16x8 b, f32x4 c) {
    return __builtin_amdgcn_mfma_f32_16x16x32_bf16(a, b, c, 0, 0, 0);
}

#define OFF_NE  0
#define OFF_ES  24576
#define OFF_E2  36864
#define OFF_A1  40960
#define OFF_AS  43008
#define OFF_EJ1 44032
#define OFF_EI1 48128
#define OFF_EJ2 52224
#define OFF_EI2 54272
#define WS_UNITS 7040

#define P2_NSB  0
#define P2_NEB  16384
#define P2_ESB  32768
#define P2_NSYM 40960
#define P2_UNITS 17408
#define SCR2_BYTES  278528
#define BASES_BYTES 1310720
#define SYMB_BYTES  1572864
#define WS_NEEDED   3274752

__global__ __launch_bounds__(256) void prepAll(
    const float* __restrict__ w_ne, const float* __restrict__ w_es,
    const float* __restrict__ w_e2, const float* __restrict__ w_a1,
    const float* __restrict__ w_as, const float* __restrict__ w_ns,
    const float* __restrict__ w_nsym,
    unsigned short* __restrict__ wsb, unsigned short* __restrict__ scr2)
{
    if (blockIdx.x < 28) {
        int u = blockIdx.x * 256 + threadIdx.x;
        if (u >= WS_UNITS) return;
        const float* w; int N, k0, KS; int uu = u;
        if (uu < 3072)      { w = w_ne; N = 128; k0 = 128; KS = 6; }
        else if (uu < 4608) { uu -= 3072; w = w_es; N = 64;  k0 = 128; KS = 6; }
        else if (uu < 5120) { uu -= 4608; w = w_e2; N = 64;  k0 = 0;   KS = 2; }
        else if (uu < 5376) { uu -= 5120; w = w_a1; N = 64;  k0 = 0;   KS = 1; }
        else if (uu < 5504) { uu -= 5376; w = w_as; N = 32;  k0 = 0;   KS = 1; }
        else if (uu < 6016) { uu -= 5504; w = w_a1; N = 64;  k0 = 160; KS = 2; }
        else if (uu < 6528) { uu -= 6016; w = w_a1; N = 64;  k0 = 224; KS = 2; }
        else if (uu < 6784) { uu -= 6528; w = w_as; N = 32;  k0 = 160; KS = 2; }
        else                { uu -= 6784; w = w_as; N = 32;  k0 = 224; KS = 2; }
        int lane = uu & 63, rest = uu >> 6;
        int ks = rest % KS, nt = rest / KS;
        int k = k0 + ks * 32 + ((lane >> 4) << 3);
        int n = nt * 16 + (lane & 15);
        us8 o;
        #pragma unroll
        for (int t = 0; t < 8; ++t) o[t] = f2bf(w[(size_t)(k + t) * N + n]);
        *(us8*)&wsb[(size_t)u * 8] = o;
    } else {
        int u = (blockIdx.x - 28) * 256 + threadIdx.x;
        if (u >= P2_UNITS) return;
        const float* w; int N, KS; int uu = u;
        if (uu < 2048)      { w = w_ns;   N = 128; KS = 4; }
        else if (uu < 4096) { uu -= 2048; w = w_ne;   N = 128; KS = 4; }
        else if (uu < 5120) { uu -= 4096; w = w_es;   N = 64;  KS = 4; }
        else                { uu -= 5120; w = w_nsym; N = 128; KS = 24; }
        int lane = uu & 63, rest = uu >> 6;
        int ks = rest % KS, nt = rest / KS;
        int k = ks * 32 + ((lane >> 4) << 3);
        int n = nt * 16 + (lane & 15);
        us8 o;
        #pragma unroll
        for (int t = 0; t < 8; ++t) o[t] = f2bf(w[(size_t)(k + t) * N + n]);
        *(us8*)&scr2[(size_t)u * 8] = o;
    }
}

__global__ __launch_bounds__(256) void kernelBases(
    const float* __restrict__ node_ext, const unsigned short* __restrict__ scr2,
    const float* __restrict__ b_ns, const float* __restrict__ b_ne,
    const float* __restrict__ b_es, float* __restrict__ bases)
{
    __shared__ __align__(16) unsigned short s_N[16][136];
    const int b = blockIdx.x, tid = threadIdx.x, L0 = b * 16;
    for (int v = tid; v < 2048; v += 256)
        s_N[v >> 7][v & 127] = f2bf(node_ext[(size_t)(L0 + (v >> 7)) * 128 + (v & 127)]);
    __syncthreads();
    const int wv = tid >> 6, ln = tid & 63, lg = ln >> 4, lr = ln & 15;
    f32x4 acc[5];
    #pragma unroll
    for (int n = 0; n < 5; ++n) acc[n] = (f32x4){0.f,0.f,0.f,0.f};
    #pragma unroll
    for (int ks = 0; ks < 4; ++ks) {
        bf16x8 a = *(const bf16x8*)&s_N[lr][ks*32 + lg*8];
        #pragma unroll
        for (int ntl = 0; ntl < 5; ++ntl) {
            int t = wv * 5 + ntl;
            size_t eoff;
            if      (t < 8)  eoff = P2_NSB + (size_t)((t*4+ks)*64+ln)*8;
            else if (t < 16) eoff = P2_NEB + (size_t)(((t-8)*4+ks)*64+ln)*8;
            else             eoff = P2_ESB + (size_t)(((t-16)*4+ks)*64+ln)*8;
            bf16x8 bb = *(const bf16x8*)&scr2[eoff];
            acc[ntl] = MFMA(a, bb, acc[ntl]);
        }
    }
    #pragma unroll
    for (int ntl = 0; ntl < 5; ++ntl) {
        int t = wv * 5 + ntl;
        int col = t * 16 + lr;
        float bias = (col < 128) ? b_ns[col] : (col < 256) ? b_ne[col-128] : b_es[col-256];
        #pragma unroll
        for (int r = 0; r < 4; ++r)
            bases[(size_t)(L0 + lg*4 + r) * 320 + col] = acc[ntl][r] + bias;
    }
}

__global__ __launch_bounds__(512, 8) void kernelA(
    const float* __restrict__ node_ext, const float* __restrict__ edge,
    const float* __restrict__ h2, const int* __restrict__ nlist,
    const float* __restrict__ sw, const unsigned short* __restrict__ wsb,
    const float* __restrict__ bases, unsigned short* __restrict__ symb,
    const float* __restrict__ b_ea2,
    const float* __restrict__ res_n0, const float* __restrict__ res_n2,
    const float* __restrict__ res_e0, const float* __restrict__ res_e1,
    float* __restrict__ out_n, float* __restrict__ out_e)
{
    __shared__ __align__(16) unsigned short s_X[64][200];
    __shared__ float s_h2g2[3][192];
    __shared__ float s_base[320];
    __shared__ float s_ne[128];
    __shared__ float s_nodef[128];
    __shared__ float s_sw[64];
    __shared__ float s_h2w[192];
    __shared__ int   s_nl[64];

    const int l = blockIdx.x, tid = threadIdx.x;

    if (tid < 64) {
        s_nl[tid] = nlist[l*64 + tid];
        s_base[256 + tid] = bases[(size_t)l * 320 + 256 + tid];   // esb section
    }
    else if (tid < 192) s_nodef[tid - 64] = node_ext[(size_t)l*128 + (tid - 64)];
    else if (tid < 256) s_sw[tid - 192] = sw[l*64 + (tid - 192)];
    else s_base[tid - 256] = bases[(size_t)l * 320 + (tid - 256)];  // tid 256..511 -> 0..255
    __syncthreads();

    for (int v = tid; v < 8192; v += 512) {
        int n = v >> 7, j = v & 127;
        s_X[n][j] = f2bf(node_ext[(size_t)s_nl[n] * 128 + j]);
    }
    for (int v = tid; v < 4096; v += 512)
        s_X[v >> 6][128 + (v & 63)] = f2bf(edge[(size_t)l * 4096 + v]);
    if (tid < 192) s_h2w[tid] = h2[(size_t)l * 192 + tid] * s_sw[tid / 3];
    __syncthreads();

    // ---- h2g2 (fp32 VALU, 4-way ILP)
    for (int v = tid; v < 576; v += 512) {
        int c = v / 192, d = v % 192;
        float p0 = 0.f, p1 = 0.f, p2 = 0.f, p3 = 0.f;
        for (int n = 0; n < 64; n += 4) {
            p0 = fmaf(s_h2w[n * 3 + c],       bf2f(s_X[n][d]),     p0);
            p1 = fmaf(s_h2w[(n + 1) * 3 + c], bf2f(s_X[n + 1][d]), p1);
            p2 = fmaf(s_h2w[(n + 2) * 3 + c], bf2f(s_X[n + 2][d]), p2);
            p3 = fmaf(s_h2w[(n + 3) * 3 + c], bf2f(s_X[n + 3][d]), p3);
        }
        s_h2g2[c][d] = ((p0 + p1) + (p2 + p3)) * 0.125f;   // 1/sqrt(64)
    }
    __syncthreads();

    const int wv = tid >> 6, ln = tid & 63, lg = ln >> 4, lr = ln & 15;

    // ---- NE: wave wv owns n-tile nt = wv (8 waves x 16 cols = 128)
    {
        f32x4 acc[4];
        #pragma unroll
        for (int m = 0; m < 4; ++m) acc[m] = (f32x4){0.f, 0.f, 0.f, 0.f};
        #pragma unroll
        for (int ks = 0; ks < 6; ++ks) {
            bf16x8 b = *(const bf16x8*)&wsb[OFF_NE + (size_t)((wv * 6 + ks) * 64 + ln) * 8];
            #pragma unroll
            for (int m = 0; m < 4; ++m) {
                bf16x8 a = *(const bf16x8*)&s_X[m * 16 + lr][ks * 32 + lg * 8];
                acc[m] = MFMA(a, b, acc[m]);
            }
        }
        int col = wv * 16 + lr;
        float base = s_base[128 + col];
        float cs = 0.f;
        #pragma unroll
        for (int m = 0; m < 4; ++m)
            #pragma unroll
            for (int r = 0; r < 4; ++r)
                cs = fmaf(silu(base + acc[m][r]), s_sw[m * 16 + lg * 4 + r], cs);
        cs += __shfl_xor(cs, 16);
        cs += __shfl_xor(cs, 32);
        if (lg == 0) s_ne[col] = cs;
    }

    // ---- ES + E2: wave pair: nt = wv>>1, m-half = wv&1 (m0 = 2*(wv&1))
    {
        const int nt = wv >> 1, m0 = (wv & 1) * 2;
        f32x4 aes[2], ae2[2];
        #pragma unroll
        for (int mm = 0; mm < 2; ++mm) {
            aes[mm] = (f32x4){0.f, 0.f, 0.f, 0.f};
            ae2[mm] = (f32x4){0.f, 0.f, 0.f, 0.f};
        }
        #pragma unroll
        for (int ks = 0; ks < 6; ++ks) {
            bf16x8 b = *(const bf16x8*)&wsb[OFF_ES + (size_t)((nt * 6 + ks) * 64 + ln) * 8];
            bf16x8 a[2];
            #pragma unroll
            for (int mm = 0; mm < 2; ++mm)
                a[mm] = *(const bf16x8*)&s_X[(m0 + mm) * 16 + lr][ks * 32 + lg * 8];
            #pragma unroll
            for (int mm = 0; mm < 2; ++mm) aes[mm] = MFMA(a[mm], b, aes[mm]);
            if (ks >= 4) {
                bf16x8 b2 = *(const bf16x8*)&wsb[OFF_E2 + (size_t)((nt * 2 + (ks - 4)) * 64 + ln) * 8];
                #pragma unroll
                for (int mm = 0; mm < 2; ++mm)
                    if (m0 + mm > 0) ae2[mm] = MFMA(a[mm], b2, ae2[mm]);
            }
        }
        int o = nt * 16 + lr;
        float esb = s_base[256 + o];
        float re0 = res_e0[o], re1 = res_e1[o], be2 = b_ea2[o];
        #pragma unroll
        for (int mm = 0; mm < 2; ++mm) {
            int m = m0 + mm;
            #pragma unroll
            for (int r = 0; r < 4; ++r) {
                int n = m * 16 + lg * 4 + r;
                size_t gi = (size_t)l * 4096 + (size_t)n * 64 + o;
                float val = bf2f(s_X[n][128 + o]) + re0 * silu(esb + aes[mm][r]);
                if (m > 0) val = fmaf(re1, silu(be2 + ae2[mm][r]), val);
                out_e[gi] = val;
            }
        }
    }

    // ---- sym (grrg) -> bf16 symb scratch
    for (int v = tid; v < 768; v += 512) {
        float p;
        if (v < 256) {
            int a = v >> 6, d = v & 63;
            p = s_h2g2[0][128 + a] * s_h2g2[0][128 + d]
              + s_h2g2[1][128 + a] * s_h2g2[1][128 + d]
              + s_h2g2[2][128 + a] * s_h2g2[2][128 + d];
        } else {
            int v2 = v - 256; int a = v2 >> 7, d = v2 & 127;
            p = s_h2g2[0][a] * s_h2g2[0][d]
              + s_h2g2[1][a] * s_h2g2[1][d]
              + s_h2g2[2][a] * s_h2g2[2][d];
        }
        symb[(size_t)l * 768 + v] = f2bf(p * (1.f / 3.f));
    }
    __syncthreads();

    if (tid < 128) {   // out_n partial: res_n1*silu(nsym) added by kernelNsym
        float ne = s_ne[tid] * (1.f / 64.f);
        float v = s_nodef[tid];
        v = fmaf(res_n0[tid], silu(s_base[tid]), v);
        v = fmaf(res_n2[tid], ne, v);
        out_n[(size_t)l * 128 + tid] = v;
    }
}

__global__ __launch_bounds__(256) void kernelNsym(
    const unsigned short* __restrict__ symb, const unsigned short* __restrict__ scr2,
    const float* __restrict__ b_nsym, const float* __restrict__ res_n1,
    float* __restrict__ out_n)
{
    const int b = blockIdx.x, tid = threadIdx.x, L0 = b * 16;
    const int wv = tid >> 6, ln = tid & 63, lg = ln >> 4, lr = ln & 15;
    f32x4 acc[2];
    acc[0] = (f32x4){0.f,0.f,0.f,0.f};
    acc[1] = (f32x4){0.f,0.f,0.f,0.f};
    for (int ks = 0; ks < 24; ++ks) {
        bf16x8 a = *(const bf16x8*)&symb[(size_t)(L0 + lr) * 768 + ks*32 + lg*8];
        #pragma unroll
        for (int nt = 0; nt < 2; ++nt) {
            bf16x8 bb = *(const bf16x8*)&scr2[P2_NSYM + (size_t)(((wv*2+nt)*24+ks)*64+ln)*8];
            acc[nt] = MFMA(a, bb, acc[nt]);
        }
    }
    #pragma unroll
    for (int nt = 0; nt < 2; ++nt) {
        int col = (wv*2 + nt) * 16 + lr;
        float bias = b_nsym[col], rn = res_n1[col];
        #pragma unroll
        for (int r = 0; r < 4; ++r) {
            size_t idx = (size_t)(L0 + lg*4 + r) * 128 + col;
            out_n[idx] += rn * silu(acc[nt][r] + bias);
        }
    }
}

__global__ __launch_bounds__(512, 8) void kernelB(
    const float* __restrict__ node_ext, const float* __restrict__ edge,
    const float* __restrict__ angle, const float* __restrict__ a_sw,
    const unsigned short* __restrict__ wsb,
    const float* __restrict__ w_ea1, const float* __restrict__ b_ea1,
    const float* __restrict__ b_ea2,
    const float* __restrict__ w_angle_self, const float* __restrict__ b_angle_self,
    const float* __restrict__ res_e1, const float* __restrict__ res_a0,
    float* __restrict__ out_e, float* __restrict__ out_a)
{
    __shared__ __align__(16) unsigned short s_ang[256][40];  // 32 -> 40 pad
    __shared__ __align__(16) unsigned short s_ea[16][72];
    __shared__ __align__(16) unsigned short s_redb[16][72];
    __shared__ float s_ej1[16][66];
    __shared__ float s_ei1[16][64];
    __shared__ float s_ej2[16][34];
    __shared__ float s_ei2[16][32];
    __shared__ float s_nt1[64];
    __shared__ float s_nt2[32];
    __shared__ float s_asw[16];
    __shared__ float s_nodef[128];

    const int l = blockIdx.x, tid = threadIdx.x;
    const int wv = tid >> 6, ln = tid & 63, lg = ln >> 4, lr = ln & 15;

    if (tid < 128) s_nodef[tid] = node_ext[(size_t)l * 128 + tid];
    else if (tid < 144) s_asw[tid - 128] = a_sw[l * 16 + (tid - 128)];
    for (int v = tid; v < 8192; v += 512)
        s_ang[v >> 5][v & 31] = f2bf(angle[(size_t)l * 8192 + v]);
    for (int v = tid; v < 1024; v += 512) s_ea[v >> 6][v & 63] = f2bf(edge[(size_t)l * 4096 + v]);
    __syncthreads();

    // angle A-frags from LDS: wave wv holds i-rows {2wv, 2wv+1}
    bf16x8 a[2];
    #pragma unroll
    for (int mm = 0; mm < 2; ++mm)
        a[mm] = *(const bf16x8*)&s_ang[(wv * 2 + mm) * 16 + lr][lg * 8];

    // ---- V0 over 8 waves: EJ1(wv0-1) EI1(wv2-3) EJ2(wv4) EI2(wv5) nt1(wv6) nt2(wv7)
    if (wv < 6) {
        bf16x8 a0 = *(const bf16x8*)&s_ea[lr][lg * 8];
        bf16x8 a1 = *(const bf16x8*)&s_ea[lr][32 + lg * 8];
        if (wv < 2) {
            #pragma unroll
            for (int ntl = 0; ntl < 2; ++ntl) {
                int nt = wv * 2 + ntl;
                f32x4 c = (f32x4){0.f, 0.f, 0.f, 0.f};
                c = MFMA(a0, *(const bf16x8*)&wsb[OFF_EJ1 + (size_t)((nt * 2 + 0) * 64 + ln) * 8], c);
                c = MFMA(a1, *(const bf16x8*)&wsb[OFF_EJ1 + (size_t)((nt * 2 + 1) * 64 + ln) * 8], c);
                #pragma unroll
                for (int r = 0; r < 4; ++r) s_ej1[lg * 4 + r][nt * 16 + lr] = c[r];
            }
        } else if (wv < 4) {
            #pragma unroll
            for (int ntl = 0; ntl < 2; ++ntl) {
                int nt = (wv - 2) * 2 + ntl;
                f32x4 c = (f32x4){0.f, 0.f, 0.f, 0.f};
                c = MFMA(a0, *(const bf16x8*)&wsb[OFF_EI1 + (size_t)((nt * 2 + 0) * 64 + ln) * 8], c);
                c = MFMA(a1, *(const bf16x8*)&wsb[OFF_EI1 + (size_t)((nt * 2 + 1) * 64 + ln) * 8], c);
                #pragma unroll
                for (int r = 0; r < 4; ++r) s_ei1[lg * 4 + r][nt * 16 + lr] = c[r];
            }
        } else if (wv == 4) {
            #pragma unroll
            for (int nt = 0; nt < 2; ++nt) {
                f32x4 c = (f32x4){0.f, 0.f, 0.f, 0.f};
                c = MFMA(a0, *(const bf16x8*)&wsb[OFF_EJ2 + (size_t)((nt * 2 + 0) * 64 + ln) * 8], c);
                c = MFMA(a1, *(const bf16x8*)&wsb[OFF_EJ2 + (size_t)((nt * 2 + 1) * 64 + ln) * 8], c);
                #pragma unroll
                for (int r = 0; r < 4; ++r) s_ej2[lg * 4 + r][nt * 16 + lr] = c[r];
            }
        } else {
            #pragma unroll
            for (int nt = 0; nt < 2; ++nt) {
                f32x4 c = (f32x4){0.f, 0.f, 0.f, 0.f};
                c = MFMA(a0, *(const bf16x8*)&wsb[OFF_EI2 + (size_t)((nt * 2 + 0) * 64 + ln) * 8], c);
                c = MFMA(a1, *(const bf16x8*)&wsb[OFF_EI2 + (size_t)((nt * 2 + 1) * 64 + ln) * 8], c);
                #pragma unroll
                for (int r = 0; r < 4; ++r) s_ei2[lg * 4 + r][nt * 16 + lr] = c[r];
            }
        }
    } else if (wv == 6) {
        float p = b_ea1[ln];
        for (int k = 0; k < 128; ++k) p = fmaf(s_nodef[k], w_ea1[(32 + k) * 64 + ln], p);
        s_nt1[ln] = p;
    } else {
        if (ln < 32) {
            float p = b_angle_self[ln];
            for (int k = 0; k < 128; ++k) p = fmaf(s_nodef[k], w_angle_self[(32 + k) * 32 + ln], p);
            s_nt2[ln] = p;
        }
    }
    __syncthreads();

    // ---- eau + weighted jj-reduction: per (mm, nt) single MFMA + epilogue
    #pragma unroll
    for (int nt = 0; nt < 4; ++nt) {
        bf16x8 b = *(const bf16x8*)&wsb[OFF_A1 + (size_t)(nt * 64 + ln) * 8];
        #pragma unroll
        for (int mm = 0; mm < 2; ++mm) {
            f32x4 c = MFMA(a[mm], b, (f32x4){0.f, 0.f, 0.f, 0.f});
            int i = wv * 2 + mm;
            int o = nt * 16 + lr;
            float b0 = s_nt1[o] + s_ei1[i][o];
            float ps = 0.f;
            #pragma unroll
            for (int r = 0; r < 4; ++r) {
                int jj = lg * 4 + r;
                ps = fmaf(silu(c[r] + b0 + s_ej1[jj][o]), s_asw[jj], ps);
            }
            ps += __shfl_xor(ps, 16);
            ps += __shfl_xor(ps, 32);
            if (lg == 0) s_redb[i][o] = f2bf(ps * s_asw[i] * 0.25f);  // /sqrt(A_SEL)
        }
    }
    // ---- angle_self + a_updated: residual from LDS bf16 (no 2nd global read)
    #pragma unroll
    for (int nt = 0; nt < 2; ++nt) {
        bf16x8 b = *(const bf16x8*)&wsb[OFF_AS + (size_t)(nt * 64 + ln) * 8];
        #pragma unroll
        for (int mm = 0; mm < 2; ++mm) {
            f32x4 c = MFMA(a[mm], b, (f32x4){0.f, 0.f, 0.f, 0.f});
            int i = wv * 2 + mm;
            int o = nt * 16 + lr;
            float b0 = s_nt2[o] + s_ei2[i][o];
            float ra = res_a0[o];
            #pragma unroll
            for (int r = 0; r < 4; ++r) {
                int jj = lg * 4 + r;
                size_t gi = (size_t)l * 8192 + (size_t)(i * 16 + jj) * 32 + o;
                out_a[gi] = bf2f(s_ang[i * 16 + jj][o]) + ra * silu(c[r] + b0 + s_ej2[jj][o]);
            }
        }
    }
    __syncthreads();

    // ---- e_angle rows n<16: waves 0..3, one n-tile each
    if (wv < 4) {
        bf16x8 a0 = *(const bf16x8*)&s_redb[lr][lg * 8];
        bf16x8 a1 = *(const bf16x8*)&s_redb[lr][32 + lg * 8];
        const int nt = wv;
        f32x4 c = (f32x4){0.f, 0.f, 0.f, 0.f};
        c = MFMA(a0, *(const bf16x8*)&wsb[OFF_E2 + (size_t)((nt * 2 + 0) * 64 + ln) * 8], c);
        c = MFMA(a1, *(const bf16x8*)&wsb[OFF_E2 + (size_t)((nt * 2 + 1) * 64 + ln) * 8], c);
        int o = nt * 16 + lr;
        float be = b_ea2[o], re1 = res_e1[o];
        #pragma unroll
        for (int r = 0; r < 4; ++r) {
            int n = lg * 4 + r;
            size_t gi = (size_t)l * 4096 + (size_t)n * 64 + o;
            out_e[gi] += re1 * silu(be + c[r]);
        }
    }
}

extern "C" void kernel_launch(void* const* d_in, const int* in_sizes, int n_in,
                              void* d_out, int out_size, void* d_ws, size_t ws_size,
                              hipStream_t stream)
{
    const float* node_ext     = (const float*)d_in[0];
    const float* edge         = (const float*)d_in[1];
    const float* h2           = (const float*)d_in[2];
    const float* angle        = (const float*)d_in[3];
    const int*   nlist        = (const int*)d_in[4];
    const float* sw           = (const float*)d_in[6];
    const float* a_sw         = (const float*)d_in[8];
    const float* w_node_self  = (const float*)d_in[9];
    const float* b_node_self  = (const float*)d_in[10];
    const float* w_node_sym   = (const float*)d_in[11];
    const float* b_node_sym   = (const float*)d_in[12];
    const float* w_node_edge  = (const float*)d_in[13];
    const float* b_node_edge  = (const float*)d_in[14];
    const float* w_edge_self  = (const float*)d_in[15];
    const float* b_edge_self  = (const float*)d_in[16];
    const float* w_ea1        = (const float*)d_in[17];
    const float* b_ea1        = (const float*)d_in[18];
    const float* w_ea2        = (const float*)d_in[19];
    const float* b_ea2        = (const float*)d_in[20];
    const float* w_angle_self = (const float*)d_in[21];
    const float* b_angle_self = (const float*)d_in[22];
    const float* res_n0       = (const float*)d_in[23];
    const float* res_n1       = (const float*)d_in[24];
    const float* res_n2       = (const float*)d_in[25];
    const float* res_e0       = (const float*)d_in[26];
    const float* res_e1       = (const float*)d_in[27];
    const float* res_a0       = (const float*)d_in[28];

    float* out_n = (float*)d_out;
    float* out_e = out_n + 1024 * 128;
    float* out_a = out_e + 1024 * 64 * 64;
    unsigned short* wsb = (unsigned short*)d_ws;

    char* scrbase = (ws_size >= (size_t)WS_NEEDED) ? ((char*)d_ws + 112640)
                                                   : (char*)out_a;
    unsigned short* scr2 = (unsigned short*)scrbase;
    float* bases = (float*)(scrbase + SCR2_BYTES);
    unsigned short* symb = (unsigned short*)(scrbase + SCR2_BYTES + BASES_BYTES);
    (void)in_sizes; (void)n_in; (void)out_size;

    hipLaunchKernelGGL(prepAll, dim3(96), dim3(256), 0, stream,
        w_node_edge, w_edge_self, w_ea2, w_ea1, w_angle_self, w_node_self, w_node_sym,
        wsb, scr2);

    hipLaunchKernelGGL(kernelBases, dim3(64), dim3(256), 0, stream,
        node_ext, scr2, b_node_self, b_node_edge, b_edge_self, bases);

    hipLaunchKernelGGL(kernelA, dim3(1024), dim3(512), 0, stream,
        node_ext, edge, h2, nlist, sw, wsb, bases, symb, b_ea2,
        res_n0, res_n2, res_e0, res_e1, out_n, out_e);

    hipLaunchKernelGGL(kernelNsym, dim3(64), dim3(256), 0, stream,
        symb, scr2, b_node_sym, res_n1, out_n);

    hipLaunchKernelGGL(kernelB, dim3(1024), dim3(512), 0, stream,
        node_ext, edge, angle, a_sw, wsb,
        w_ea1, b_ea1, b_ea2, w_angle_self, b_angle_self,
        res_e1, res_a0, out_e, out_a);
}